// Round 1
// baseline (3870.460 us; speedup 1.0000x reference)
//
#include <hip/hip_runtime.h>

// Polarisation solver: E0 edge pass + 7 Jacobi iterations of mu = alpha*(E0 - A*mu),
// energy = -0.5 mu.E0. Edge coefficients recomputed per pass (VALU is free vs HBM).

static constexpr float INV_B  = 1.0f / 0.52917721067f;            // 1/BOHR
static constexpr float INV_B3 = INV_B * INV_B * INV_B;            // 1/BOHR^3
static constexpr float DM = 0.39f;                                 // DAMP_MUTUAL
static constexpr float DF = 0.7f;                                  // DAMP_FIELD
static constexpr int   NITER = 7;

// ---- E0 = segment_sum over src of (l3_f * q[dst] * inv_r3) * vec_ij ----
__global__ void e0_kernel(const int* __restrict__ esrc, const int* __restrict__ edst,
                          const float* __restrict__ dist, const float* __restrict__ vec,
                          const float* __restrict__ pol, const float* __restrict__ chg,
                          float4* __restrict__ E0, int E)
{
    int e = blockIdx.x * blockDim.x + threadIdx.x;
    if (e >= E) return;
    int s = esrc[e], d = edst[e];
    float r  = dist[e] * INV_B;
    float vx = vec[3*e+0] * INV_B;
    float vy = vec[3*e+1] * INV_B;
    float vz = vec[3*e+2] * INV_B;
    float ps = pol[s] * INV_B3;
    float pd = pol[d] * INV_B3;
    float r3 = r * r * r;
    float u  = r3 * rsqrtf(ps * pd);          // uij3
    float l3f = 1.0f - __expf(-DF * u);
    float inv_r3 = 1.0f / r3;
    float ec = l3f * chg[d] * inv_r3;
    atomicAdd(&E0[s].x, ec * vx);
    atomicAdd(&E0[s].y, ec * vy);
    atomicAdd(&E0[s].z, ec * vz);
}

// ---- mu0 = alpha * E0 ; acc = 0 ----
__global__ void init_kernel(const float* __restrict__ pol, const float4* __restrict__ E0,
                            float4* __restrict__ mu, float4* __restrict__ acc, int N)
{
    int i = blockIdx.x * blockDim.x + threadIdx.x;
    if (i >= N) return;
    float a = pol[i] * INV_B3;
    float4 e0 = E0[i];
    mu[i]  = make_float4(a * e0.x, a * e0.y, a * e0.z, 0.0f);
    acc[i] = make_float4(0.0f, 0.0f, 0.0f, 0.0f);
}

// ---- acc += t_e scattered to src; t = c1*mu_d - (c2*dot(v,mu_d))*v ----
__global__ void matvec_kernel(const int* __restrict__ esrc, const int* __restrict__ edst,
                              const float* __restrict__ dist, const float* __restrict__ vec,
                              const float* __restrict__ pol,
                              const float4* __restrict__ mu,
                              float4* __restrict__ acc, int E)
{
    int e = blockIdx.x * blockDim.x + threadIdx.x;
    if (e >= E) return;
    int s = esrc[e], d = edst[e];
    float r  = dist[e] * INV_B;
    float vx = vec[3*e+0] * INV_B;
    float vy = vec[3*e+1] * INV_B;
    float vz = vec[3*e+2] * INV_B;
    float ps = pol[s] * INV_B3;
    float pd = pol[d] * INV_B3;
    float r2 = r * r;
    float r3 = r2 * r;
    float u  = r3 * rsqrtf(ps * pd);          // uij3
    float em = __expf(-DM * u);
    float l3m = 1.0f - em;
    float l5m = 1.0f - (1.0f + DM * u) * em;  // u >= 0.5 -> no cancellation risk
    float inv_r3 = 1.0f / r3;
    float inv_r5 = inv_r3 / r2;
    float c1 = l3m * inv_r3;
    float c2 = 3.0f * l5m * inv_r5;
    float4 m = mu[d];                          // 16B gather, L2-resident (1.6MB)
    float dot = vx * m.x + vy * m.y + vz * m.z;
    float k = c2 * dot;
    atomicAdd(&acc[s].x, c1 * m.x - k * vx);
    atomicAdd(&acc[s].y, c1 * m.y - k * vy);
    atomicAdd(&acc[s].z, c1 * m.z - k * vz);
}

// ---- mu = alpha*(E0 - acc); acc = 0; optionally energy = -0.5*mu.E0 ----
__global__ void update_kernel(const float* __restrict__ pol, const float4* __restrict__ E0,
                              float4* __restrict__ acc, float4* __restrict__ mu,
                              float* __restrict__ energy, int N, int final_iter)
{
    int i = blockIdx.x * blockDim.x + threadIdx.x;
    if (i >= N) return;
    float a = pol[i] * INV_B3;
    float4 e0 = E0[i];
    float4 ac = acc[i];
    float mx = a * (e0.x - ac.x);
    float my = a * (e0.y - ac.y);
    float mz = a * (e0.z - ac.z);
    mu[i]  = make_float4(mx, my, mz, 0.0f);
    acc[i] = make_float4(0.0f, 0.0f, 0.0f, 0.0f);
    if (final_iter)
        energy[i] = -0.5f * (mx * e0.x + my * e0.y + mz * e0.z);
}

extern "C" void kernel_launch(void* const* d_in, const int* in_sizes, int n_in,
                              void* d_out, int out_size, void* d_ws, size_t ws_size,
                              hipStream_t stream)
{
    // inputs (setup_inputs order): species, edge_src, edge_dst, distances, vec, polarisability, charges
    const int*   esrc = (const int*)  d_in[1];
    const int*   edst = (const int*)  d_in[2];
    const float* dist = (const float*)d_in[3];
    const float* vec  = (const float*)d_in[4];
    const float* pol  = (const float*)d_in[5];
    const float* chg  = (const float*)d_in[6];
    const int E = in_sizes[1];
    const int N = in_sizes[5];
    float* out = (float*)d_out;

    // workspace: E0 | mu | acc  (float4 each, 16B/node) = 4.8 MB total
    char* ws = (char*)d_ws;
    float4* E0  = (float4*)(ws);
    float4* mu  = (float4*)(ws + (size_t)N * 16);
    float4* acc = (float4*)(ws + (size_t)N * 32);

    hipMemsetAsync(E0, 0, (size_t)N * 16, stream);   // atomic target must start at 0

    const int EB = 256, NB = 256;
    const int EG = (E + EB - 1) / EB;
    const int NG = (N + NB - 1) / NB;

    e0_kernel<<<EG, EB, 0, stream>>>(esrc, edst, dist, vec, pol, chg, E0, E);
    init_kernel<<<NG, NB, 0, stream>>>(pol, E0, mu, acc, N);
    for (int it = 0; it < NITER; ++it) {
        matvec_kernel<<<EG, EB, 0, stream>>>(esrc, edst, dist, vec, pol, mu, acc, E);
        update_kernel<<<NG, NB, 0, stream>>>(pol, E0, acc, mu, out, N, it == NITER - 1);
    }
}

// Round 2
// 490.730 us; speedup vs baseline: 7.8872x; 7.8872x over previous
//
#include <hip/hip_runtime.h>

// Polarisation solver, CSR-gather formulation.
// Build (per call): histogram(src) -> exclusive scan -> scatter edges into
// CSR slots, pre-folding physics into payload {dst, c1, w} (20B/edge) and
// E0 terms (12B/edge). Then E0 = gather-sum, and 7 Jacobi iterations are
// pure gather passes with no atomics.

static constexpr float INV_B  = 1.0f / 0.52917721067f;            // 1/BOHR
static constexpr float INV_B3 = INV_B * INV_B * INV_B;            // 1/BOHR^3
static constexpr float DM = 0.39f;                                 // DAMP_MUTUAL
static constexpr float DF = 0.7f;                                  // DAMP_FIELD
static constexpr int   NITER = 7;
#define SCAN_B 256

// ---------------- CSR build ----------------

__global__ void hist_kernel(const int* __restrict__ esrc, int* __restrict__ cnt, int E)
{
    int e = blockIdx.x * blockDim.x + threadIdx.x;
    if (e < E) atomicAdd(&cnt[esrc[e]], 1);
}

// Block-level inclusive scan (Hillis-Steele in LDS); writes exclusive prefix
// and per-block totals. n = N+1 write range, nvalid = N read range (cnt has N).
__global__ void scan1_kernel(const int* __restrict__ cnt, int* __restrict__ excl,
                             int* __restrict__ blocksum, int n, int nvalid)
{
    __shared__ int sh[SCAN_B];
    int tid = threadIdx.x;
    int i = blockIdx.x * SCAN_B + tid;
    int v = (i < nvalid) ? cnt[i] : 0;
    sh[tid] = v;
    __syncthreads();
    for (int off = 1; off < SCAN_B; off <<= 1) {
        int t = (tid >= off) ? sh[tid - off] : 0;
        __syncthreads();
        sh[tid] += t;
        __syncthreads();
    }
    if (i < n) excl[i] = sh[tid] - v;                 // exclusive within block
    if (tid == SCAN_B - 1) blocksum[blockIdx.x] = sh[tid];
}

__global__ void scan2_kernel(int* __restrict__ blocksum, int nb)
{
    __shared__ int sh[512];
    int tid = threadIdx.x;
    int v = (tid < nb) ? blocksum[tid] : 0;
    sh[tid] = v;
    __syncthreads();
    for (int off = 1; off < 512; off <<= 1) {
        int t = (tid >= off) ? sh[tid - off] : 0;
        __syncthreads();
        sh[tid] += t;
        __syncthreads();
    }
    if (tid < nb) blocksum[tid] = sh[tid] - v;        // exclusive over blocks
}

// finalize rowptr (+= block offset) and initialize cursor = rowptr
__global__ void scan3_kernel(int* __restrict__ rowptr, const int* __restrict__ blocksum,
                             int* __restrict__ cursor, int n)
{
    int i = blockIdx.x * SCAN_B + threadIdx.x;
    if (i < n) {
        int v = rowptr[i] + blocksum[blockIdx.x];
        rowptr[i] = v;
        if (i < n - 1) cursor[i] = v;
    }
}

// Scatter edges to CSR slots; pre-fold physics.
// matvec term: t = c1*mu_d - (3*l5m*inv_r5*dot(v,mu_d))*v = c1*mu_d - (w.mu_d)*w
// with w = sqrt(3*l5m*inv_r5)*v (l5m >= 0 always).
__global__ void scatter_kernel(const int* __restrict__ esrc, const int* __restrict__ edst,
                               const float* __restrict__ dist, const float* __restrict__ vec,
                               const float* __restrict__ pol, const float* __restrict__ chg,
                               int* __restrict__ cursor,
                               int* __restrict__ dstA, float4* __restrict__ c1w,
                               float* __restrict__ e0p, int E)
{
    int e = blockIdx.x * blockDim.x + threadIdx.x;
    if (e >= E) return;
    int s = esrc[e], d = edst[e];
    float r  = dist[e] * INV_B;
    float vx = vec[3*e+0] * INV_B;
    float vy = vec[3*e+1] * INV_B;
    float vz = vec[3*e+2] * INV_B;
    float ps = pol[s] * INV_B3;
    float pd = pol[d] * INV_B3;
    float r2 = r * r;
    float r3 = r2 * r;
    float u  = r3 * rsqrtf(ps * pd);
    float em = __expf(-DM * u);
    float l3m = 1.0f - em;
    float l5m = 1.0f - (1.0f + DM * u) * em;
    float inv_r3 = 1.0f / r3;
    float inv_r5 = inv_r3 / r2;
    float c1 = l3m * inv_r3;
    float sw = sqrtf(3.0f * l5m * inv_r5);
    float l3f = 1.0f - __expf(-DF * u);
    float ec  = l3f * chg[d] * inv_r3;
    int slot = atomicAdd(&cursor[s], 1);
    dstA[slot] = d;
    c1w[slot]  = make_float4(c1, sw * vx, sw * vy, sw * vz);
    e0p[3*slot+0] = ec * vx;
    e0p[3*slot+1] = ec * vy;
    e0p[3*slot+2] = ec * vz;
}

// ---------------- gather passes (no atomics) ----------------
// 16 lanes per row, 16 rows per 256-block.

__global__ void e0gather_kernel(const int* __restrict__ rowptr, const float* __restrict__ e0p,
                                const float* __restrict__ pol,
                                float4* __restrict__ E0, float4* __restrict__ mu, int N)
{
    int tid  = threadIdx.x;
    int lane = tid & 15;
    int row  = (blockIdx.x * blockDim.x + tid) >> 4;
    if (row >= N) return;
    int r0 = rowptr[row], r1 = rowptr[row + 1];
    float sx = 0.f, sy = 0.f, sz = 0.f;
    for (int j = r0 + lane; j < r1; j += 16) {
        sx += e0p[3*j+0];
        sy += e0p[3*j+1];
        sz += e0p[3*j+2];
    }
    for (int m = 8; m >= 1; m >>= 1) {
        sx += __shfl_xor(sx, m);
        sy += __shfl_xor(sy, m);
        sz += __shfl_xor(sz, m);
    }
    if (lane == 0) {
        E0[row] = make_float4(sx, sy, sz, 0.f);
        float a = pol[row] * INV_B3;
        mu[row] = make_float4(a * sx, a * sy, a * sz, 0.f);
    }
}

__global__ void mvgather_kernel(const int* __restrict__ rowptr, const int* __restrict__ dstA,
                                const float4* __restrict__ c1w, const float4* __restrict__ E0,
                                const float* __restrict__ pol,
                                const float4* __restrict__ mu_in, float4* __restrict__ mu_out,
                                float* __restrict__ energy, int N, int final_iter)
{
    int tid  = threadIdx.x;
    int lane = tid & 15;
    int row  = (blockIdx.x * blockDim.x + tid) >> 4;
    if (row >= N) return;
    int r0 = rowptr[row], r1 = rowptr[row + 1];
    float ax = 0.f, ay = 0.f, az = 0.f;
    for (int j = r0 + lane; j < r1; j += 16) {
        int d = dstA[j];
        float4 cw = c1w[j];
        float4 m  = mu_in[d];
        float dot = cw.y * m.x + cw.z * m.y + cw.w * m.z;
        ax += cw.x * m.x - dot * cw.y;
        ay += cw.x * m.y - dot * cw.z;
        az += cw.x * m.z - dot * cw.w;
    }
    for (int msk = 8; msk >= 1; msk >>= 1) {
        ax += __shfl_xor(ax, msk);
        ay += __shfl_xor(ay, msk);
        az += __shfl_xor(az, msk);
    }
    if (lane == 0) {
        float4 e0 = E0[row];
        float a = pol[row] * INV_B3;
        float mx = a * (e0.x - ax);
        float my = a * (e0.y - ay);
        float mz = a * (e0.z - az);
        mu_out[row] = make_float4(mx, my, mz, 0.f);
        if (final_iter)
            energy[row] = -0.5f * (mx * e0.x + my * e0.y + mz * e0.z);
    }
}

// ---------------- fallback (atomic path, small ws) ----------------

__global__ void fb_e0_kernel(const int* esrc, const int* edst, const float* dist,
                             const float* vec, const float* pol, const float* chg,
                             float4* E0, int E)
{
    int e = blockIdx.x * blockDim.x + threadIdx.x;
    if (e >= E) return;
    int s = esrc[e], d = edst[e];
    float r  = dist[e] * INV_B;
    float vx = vec[3*e+0]*INV_B, vy = vec[3*e+1]*INV_B, vz = vec[3*e+2]*INV_B;
    float r3 = r*r*r;
    float u  = r3 * rsqrtf(pol[s]*INV_B3 * pol[d]*INV_B3);
    float ec = (1.0f - __expf(-DF*u)) * chg[d] / r3;
    atomicAdd(&E0[s].x, ec*vx); atomicAdd(&E0[s].y, ec*vy); atomicAdd(&E0[s].z, ec*vz);
}

__global__ void fb_init_kernel(const float* pol, const float4* E0, float4* mu, float4* acc, int N)
{
    int i = blockIdx.x * blockDim.x + threadIdx.x;
    if (i >= N) return;
    float a = pol[i]*INV_B3; float4 e0 = E0[i];
    mu[i]  = make_float4(a*e0.x, a*e0.y, a*e0.z, 0.f);
    acc[i] = make_float4(0.f,0.f,0.f,0.f);
}

__global__ void fb_matvec_kernel(const int* esrc, const int* edst, const float* dist,
                                 const float* vec, const float* pol,
                                 const float4* mu, float4* acc, int E)
{
    int e = blockIdx.x * blockDim.x + threadIdx.x;
    if (e >= E) return;
    int s = esrc[e], d = edst[e];
    float r  = dist[e]*INV_B;
    float vx = vec[3*e+0]*INV_B, vy = vec[3*e+1]*INV_B, vz = vec[3*e+2]*INV_B;
    float r2 = r*r, r3 = r2*r;
    float u  = r3 * rsqrtf(pol[s]*INV_B3 * pol[d]*INV_B3);
    float em = __expf(-DM*u);
    float c1 = (1.0f - em) / r3;
    float c2 = 3.0f * (1.0f - (1.0f + DM*u)*em) / (r3*r2);
    float4 m = mu[d];
    float k = c2 * (vx*m.x + vy*m.y + vz*m.z);
    atomicAdd(&acc[s].x, c1*m.x - k*vx);
    atomicAdd(&acc[s].y, c1*m.y - k*vy);
    atomicAdd(&acc[s].z, c1*m.z - k*vz);
}

__global__ void fb_update_kernel(const float* pol, const float4* E0, float4* acc,
                                 float4* mu, float* energy, int N, int final_iter)
{
    int i = blockIdx.x * blockDim.x + threadIdx.x;
    if (i >= N) return;
    float a = pol[i]*INV_B3; float4 e0 = E0[i]; float4 ac = acc[i];
    float mx = a*(e0.x-ac.x), my = a*(e0.y-ac.y), mz = a*(e0.z-ac.z);
    mu[i]  = make_float4(mx,my,mz,0.f);
    acc[i] = make_float4(0.f,0.f,0.f,0.f);
    if (final_iter) energy[i] = -0.5f*(mx*e0.x + my*e0.y + mz*e0.z);
}

// ---------------- launch ----------------

static inline size_t align_up(size_t x, size_t a) { return (x + a - 1) & ~(a - 1); }

extern "C" void kernel_launch(void* const* d_in, const int* in_sizes, int n_in,
                              void* d_out, int out_size, void* d_ws, size_t ws_size,
                              hipStream_t stream)
{
    // inputs: species, edge_src, edge_dst, distances, vec, polarisability, charges
    const int*   esrc = (const int*)  d_in[1];
    const int*   edst = (const int*)  d_in[2];
    const float* dist = (const float*)d_in[3];
    const float* vec  = (const float*)d_in[4];
    const float* pol  = (const float*)d_in[5];
    const float* chg  = (const float*)d_in[6];
    const int E = in_sizes[1];
    const int N = in_sizes[5];
    float* out = (float*)d_out;

    const int EB = 256, NB = 256;
    const int EG = (E + EB - 1) / EB;

    // workspace layout
    char* ws = (char*)d_ws;
    size_t off = 0;
    auto carve = [&](size_t bytes) { size_t o = off; off = align_up(off + bytes, 256); return o; };
    size_t o_rowptr  = carve((size_t)(N + 1) * 4);
    size_t o_cursor  = carve((size_t)N * 4);
    size_t o_E0      = carve((size_t)N * 16);
    size_t o_mua     = carve((size_t)N * 16);
    size_t o_mub     = carve((size_t)N * 16);
    size_t o_bsum    = carve(512 * 4);
    size_t o_dstA    = carve((size_t)E * 4);
    size_t o_c1w     = carve((size_t)E * 16);
    size_t o_e0p     = carve((size_t)E * 12);
    size_t need = off;

    if (ws_size >= need) {
        int*    rowptr = (int*)   (ws + o_rowptr);
        int*    cursor = (int*)   (ws + o_cursor);
        float4* E0     = (float4*)(ws + o_E0);
        float4* mu_a   = (float4*)(ws + o_mua);
        float4* mu_b   = (float4*)(ws + o_mub);
        int*    bsum   = (int*)   (ws + o_bsum);
        int*    dstA   = (int*)   (ws + o_dstA);
        float4* c1w    = (float4*)(ws + o_c1w);
        float*  e0p    = (float*) (ws + o_e0p);

        const int nScan = N + 1;
        const int g1 = (nScan + SCAN_B - 1) / SCAN_B;     // <= 512 for N=100k

        hipMemsetAsync(cursor, 0, (size_t)N * 4, stream);
        hist_kernel<<<EG, EB, 0, stream>>>(esrc, cursor, E);
        scan1_kernel<<<g1, SCAN_B, 0, stream>>>(cursor, rowptr, bsum, nScan, N);
        scan2_kernel<<<1, 512, 0, stream>>>(bsum, g1);
        scan3_kernel<<<g1, SCAN_B, 0, stream>>>(rowptr, bsum, cursor, nScan);
        scatter_kernel<<<EG, EB, 0, stream>>>(esrc, edst, dist, vec, pol, chg,
                                              cursor, dstA, c1w, e0p, E);

        const int rows_per_block = NB / 16;
        const int NG16 = (N + rows_per_block - 1) / rows_per_block;
        e0gather_kernel<<<NG16, NB, 0, stream>>>(rowptr, e0p, pol, E0, mu_a, N);

        float4* min_ = mu_a; float4* mout_ = mu_b;
        for (int it = 0; it < NITER; ++it) {
            mvgather_kernel<<<NG16, NB, 0, stream>>>(rowptr, dstA, c1w, E0, pol,
                                                     min_, mout_, out, N, it == NITER - 1);
            float4* t = min_; min_ = mout_; mout_ = t;
        }
    } else {
        // fallback: atomic scatter path (needs 48B/node)
        float4* E0  = (float4*)(ws);
        float4* mu  = (float4*)(ws + (size_t)N * 16);
        float4* acc = (float4*)(ws + (size_t)N * 32);
        const int NG = (N + NB - 1) / NB;
        hipMemsetAsync(E0, 0, (size_t)N * 16, stream);
        fb_e0_kernel<<<EG, EB, 0, stream>>>(esrc, edst, dist, vec, pol, chg, E0, E);
        fb_init_kernel<<<NG, NB, 0, stream>>>(pol, E0, mu, acc, N);
        for (int it = 0; it < NITER; ++it) {
            fb_matvec_kernel<<<EG, EB, 0, stream>>>(esrc, edst, dist, vec, pol, mu, acc, E);
            fb_update_kernel<<<NG, NB, 0, stream>>>(pol, E0, acc, mu, out, N, it == NITER - 1);
        }
    }
}